// Round 7
// baseline (329.662 us; speedup 1.0000x reference)
//
#include <hip/hip_runtime.h>
#include <math.h>

#define NB 64      // batch N
#define LL 128     // n_in capsules
#define DD 768     // feature dim
#define ID 64      // in_dim
#define OD 64      // out_dim
#define NO 32      // n_out
#define EPSF 1e-8f

typedef unsigned short ushort_t;
typedef __attribute__((ext_vector_type(8))) short bf16x8;
typedef __attribute__((ext_vector_type(4))) float f32x4;

// ws layout (floats):
//  V     : 16777216 fp32  [n][l][o*64+j]
//    Cpart/apart alias V front (consumed pre-k1)
//  Ah/Al : 2 x 524288 ushorts, fragment-linear [l][ks][mt][mr][q][i8]
//  f_a   : 8192
//  S1p/S2p : 8-chunk partials [c][n][o][j] (1048576 each)
//  dnp/aUp : 16384 each
//  mu_s/i2v_s : 131072 each ; cterm : 2048 ; cnt : 64 ints

__device__ __forceinline__ float gelu_exact(float v) {
  return 0.5f * v * (1.0f + erff(v * 0.70710678118654752440f));
}
__device__ __forceinline__ float sigmoidf_(float z) {
  return 1.0f / (1.0f + __expf(-z));
}
__device__ __forceinline__ unsigned short f2bf(float f) {  // RNE
  unsigned u = __float_as_uint(f);
  unsigned r = (u + 0x7FFFu + ((u >> 16) & 1u)) >> 16;
  return (unsigned short)r;
}
__device__ __forceinline__ float bf2f(unsigned short s) {
  return __uint_as_float(((unsigned)s) << 16);
}

// ---------------- k0a: split-K partial GEMM for the projections (unchanged).
__global__ __launch_bounds__(256) void k0a_proj(
    const float* __restrict__ x, const float* __restrict__ Wscore,
    const float* __restrict__ Wcap,
    float* __restrict__ Cpart, float* __restrict__ apart)
{
  const int l  = blockIdx.x & 127;
  const int kc = blockIdx.x >> 7;
  const int t = threadIdx.x;
  const int tn = t >> 4;
  const int ti = t & 15;
  __shared__ float Xs[64][68];
  __shared__ float Ws[64][68];
  __shared__ float Ss[64];
  float C[4][4] = {{0.f}};
  float asum[4] = {0.f, 0.f, 0.f, 0.f};

  for (int kt = 0; kt < 2; ++kt) {
    const int kbase = kc * 128 + kt * 64;
#pragma unroll
    for (int r = 0; r < 4; ++r) {
      const int flat = r * 1024 + t * 4;
      const int p = flat >> 6, qq = flat & 63;
      *(float4*)&Xs[p][qq] = *(const float4*)&x[(p * LL + l) * DD + kbase + qq];
      *(float4*)&Ws[p][qq] = *(const float4*)&Wcap[(l * DD + kbase + p) * ID + qq];
    }
    if (t < 16)
      *(float4*)&Ss[4 * t] = *(const float4*)&Wscore[l * DD + kbase + 4 * t];
    __syncthreads();
#pragma unroll 8
    for (int k = 0; k < 64; ++k) {
      float av[4];
      av[0] = Xs[4 * tn + 0][k];
      av[1] = Xs[4 * tn + 1][k];
      av[2] = Xs[4 * tn + 2][k];
      av[3] = Xs[4 * tn + 3][k];
      const float4 b = *(const float4*)&Ws[k][4 * ti];
      const float sk = Ss[k];
#pragma unroll
      for (int a = 0; a < 4; ++a) {
        C[a][0] = fmaf(av[a], b.x, C[a][0]);
        C[a][1] = fmaf(av[a], b.y, C[a][1]);
        C[a][2] = fmaf(av[a], b.z, C[a][2]);
        C[a][3] = fmaf(av[a], b.w, C[a][3]);
        asum[a] = fmaf(av[a], sk, asum[a]);
      }
    }
    __syncthreads();
  }
#pragma unroll
  for (int a = 0; a < 4; ++a)
    *(float4*)&Cpart[kc * 524288 + (l * 64 + 4 * tn + a) * 64 + 4 * ti] =
        make_float4(C[a][0], C[a][1], C[a][2], C[a][3]);
  if (ti == 0) {
#pragma unroll
    for (int a = 0; a < 4; ++a)
      apart[kc * 8192 + l * 64 + 4 * tn + a] = asum[a];
  }
}

// ---------------- k0bc: fused (k0b reduce+gelu -> Ah/Al) + (k0c -> f_a) +
// cnt zeroing.  Blocks 0..31 additionally do the f_a element; block 32
// zeroes the per-n finisher counters.  Saves one launch (~5us node cost).
__global__ __launch_bounds__(256) void k0bc(
    const float* __restrict__ Cpart, const float* __restrict__ Bcap,
    const float* __restrict__ apart, const float* __restrict__ Bscore,
    ushort_t* __restrict__ Ah, ushort_t* __restrict__ Al,
    float* __restrict__ f_a, int* __restrict__ cnt)
{
  const int bid = blockIdx.x;
  const int t = threadIdx.x;
  const int e = (bid * 256 + t) * 4;
  float4 s = *(const float4*)&Cpart[e];
#pragma unroll
  for (int kc = 1; kc < 6; ++kc) {
    const float4 p = *(const float4*)&Cpart[kc * 524288 + e];
    s.x += p.x; s.y += p.y; s.z += p.z; s.w += p.w;
  }
  const int l = e >> 12;
  const int n = (e >> 6) & 63;
  const int i0 = e & 63;
  const float4 bc = *(const float4*)&Bcap[l * 64 + i0];
  float m[4] = {gelu_exact(s.x + bc.x), gelu_exact(s.y + bc.y),
                gelu_exact(s.z + bc.z), gelu_exact(s.w + bc.w)};
  ushort4 h, lo;
  h.x = f2bf(m[0]); lo.x = f2bf(m[0] - bf2f(h.x));
  h.y = f2bf(m[1]); lo.y = f2bf(m[1] - bf2f(h.y));
  h.z = f2bf(m[2]); lo.z = f2bf(m[2] - bf2f(h.z));
  h.w = f2bf(m[3]); lo.w = f2bf(m[3] - bf2f(h.w));
  const int off = l * 4096 + (i0 >> 5) * 2048 + (n >> 4) * 512 + (n & 15) * 32 +
                  ((i0 >> 3) & 3) * 8 + (i0 & 7);
  *(ushort4*)&Ah[off] = h;
  *(ushort4*)&Al[off] = lo;

  if (bid < 32) {                     // k0c work
    const int e2 = bid * 256 + t;
    float ss = 0.f;
#pragma unroll
    for (int kc = 0; kc < 6; ++kc) ss += apart[kc * 8192 + e2];
    f_a[e2] = sigmoidf_(ss + Bscore[e2 >> 6]);
  }
  if (bid == 32 && t < 64) cnt[t] = 0;
}

// ---------------- k1: V = mu_in @ Wvote + Bvote (unchanged from R6 v6).
__global__ __launch_bounds__(256) void k1_votes(
    const ushort_t* __restrict__ Ah, const ushort_t* __restrict__ Al,
    const float* __restrict__ Wvote, const float* __restrict__ Bvote,
    float* __restrict__ V)
{
  const int t = threadIdx.x;
  const int w = t >> 6;
  const int lane = t & 63;
  const int g = blockIdx.x * 4 + w;       // 0..8191
  const int pair = g >> 1;                // l*NO + o
  const int jh = g & 1;                   // j-half
  const int l = pair >> 5;
  const int mr = lane & 15, q = lane >> 4;

  __shared__ unsigned HL_all[4][1024];    // per-wave staging, 4 KiB/wave
  unsigned* HL = HL_all[w];

  const float* Wt = Wvote + (size_t)pair * 4096 + jh * 32;   // [i][j-half]
  const int afoff = mr * 32 + q * 8;

  float bv[2];
#pragma unroll
  for (int nt = 0; nt < 2; ++nt)
    bv[nt] = Bvote[pair * 64 + jh * 32 + 16 * nt + mr];

  f32x4 acc[4][2];
#pragma unroll
  for (int mt = 0; mt < 4; ++mt)
#pragma unroll
    for (int nt = 0; nt < 2; ++nt) {
      f32x4 z = {0.f, 0.f, 0.f, 0.f};
      acc[mt][nt] = z;
    }

#pragma unroll 1
  for (int ks = 0; ks < 2; ++ks) {
#pragma unroll
    for (int f = 0; f < 4; ++f) {
      const int idx = f * 64 + lane;
      const int r = idx >> 3;                       // row 0..31
      const int c4 = (idx & 7) * 4;                 // col 0..28
      const float4 v4 = *(const float4*)&Wt[ks * 2048 + r * 64 + c4];
      const int jc = c4 ^ ((r & 8) << 1);           // XOR-swizzled col base
      const float e4[4] = {v4.x, v4.y, v4.z, v4.w};
      unsigned pk[4];
#pragma unroll
      for (int d = 0; d < 4; ++d) {
        const unsigned short hi = f2bf(e4[d]);
        const unsigned short lo = f2bf(e4[d] - bf2f(hi));
        pk[d] = (unsigned)hi | ((unsigned)lo << 16);
      }
      *(uint4*)&HL[r * 32 + jc] = make_uint4(pk[0], pk[1], pk[2], pk[3]);
    }

    bf16x8 afh[4], afl[4];
#pragma unroll
    for (int mt = 0; mt < 4; ++mt) {
      const int off = l * 4096 + ks * 2048 + mt * 512 + afoff;
      afh[mt] = *(const bf16x8*)&Ah[off];
      afl[mt] = *(const bf16x8*)&Al[off];
    }

#pragma unroll
    for (int nt = 0; nt < 2; ++nt) {
      const int j = 16 * nt + mr;
      unsigned wv[8];
#pragma unroll
      for (int d = 0; d < 8; ++d) {
        const int ii = q * 8 + d;
        wv[d] = HL[ii * 32 + (j ^ ((ii & 8) << 1))];
      }
      union { ushort_t u[8]; bf16x8 v; } bh, bl;
#pragma unroll
      for (int d = 0; d < 8; ++d) {
        bh.u[d] = (ushort_t)(wv[d] & 0xffffu);
        bl.u[d] = (ushort_t)(wv[d] >> 16);
      }
#pragma unroll
      for (int mt = 0; mt < 4; ++mt) {
        acc[mt][nt] = __builtin_amdgcn_mfma_f32_16x16x32_bf16(
            afh[mt], bh.v, acc[mt][nt], 0, 0, 0);
        acc[mt][nt] = __builtin_amdgcn_mfma_f32_16x16x32_bf16(
            afh[mt], bl.v, acc[mt][nt], 0, 0, 0);
        acc[mt][nt] = __builtin_amdgcn_mfma_f32_16x16x32_bf16(
            afl[mt], bh.v, acc[mt][nt], 0, 0, 0);
      }
    }
  }

  float* T = (float*)HL;
#pragma unroll
  for (int mt = 0; mt < 4; ++mt) {
#pragma unroll
    for (int nt = 0; nt < 2; ++nt)
#pragma unroll
      for (int r = 0; r < 4; ++r)
        T[(4 * q + r) * 36 + 16 * nt + mr] = acc[mt][nt][r] + bv[nt];
#pragma unroll
    for (int rr = 0; rr < 2; ++rr) {
      const int row = rr * 8 + (lane >> 3);
      const int c4e = (lane & 7) * 4;
      const float4 vv = *(const float4*)&T[row * 36 + c4e];
      const size_t base = (size_t)(16 * mt + row) * (LL * NO * OD) +
                          (size_t)pair * 64 + jh * 32 + c4e;
      *(float4*)&V[base] = vv;
    }
  }
}

// ---------------- k3f: fused EM step (k3 partials + opportunistic-last-block
// k4 finalize).  MODE 0=iter1(uniform R, accum S2), 1=iter2(softmax, accum
// S2), 2=iter3(softmax, NO S2 -- reference discards final var_out; outputs
// a_out/mu_out only).  Per-n finisher: after partial stores + syncthreads
// (drains stores, vmcnt0), t0 does threadfence+atomicAdd(cnt[n]); the block
// seeing old==MODE*8+7 acquires and runs the (deterministic, fixed-order)
// k4 v1 reduction.  No spinning -> deadlock-free; removes 3 launches.
template <int MODE>
__global__ __launch_bounds__(256) void k3f_em(
    const float* __restrict__ V, const float* __restrict__ f_a,
    const float* __restrict__ beta_use, const float* __restrict__ beta_ign,
    float* __restrict__ mu_s, float* __restrict__ i2v_s,
    float* __restrict__ cterm,
    float* __restrict__ S1p, float* __restrict__ S2p,
    float* __restrict__ dnp, float* __restrict__ aUp,
    float* __restrict__ out, int* __restrict__ cnt)
{
  const int n = blockIdx.x >> 3;
  const int c = blockIdx.x & 7;
  const int t = threadIdx.x;
  const int o = t >> 3, q = t & 7;
  __shared__ float ttl[8][32];
  __shared__ float rA[128];
  __shared__ int lastFlag;

  float mu8[8], iv8[8];
  float ct = 0.f;
  if (MODE != 0) {
    const float4 a0 = *(const float4*)&mu_s[n * 2048 + t * 8];
    const float4 a1 = *(const float4*)&mu_s[n * 2048 + t * 8 + 4];
    mu8[0] = a0.x; mu8[1] = a0.y; mu8[2] = a0.z; mu8[3] = a0.w;
    mu8[4] = a1.x; mu8[5] = a1.y; mu8[6] = a1.z; mu8[7] = a1.w;
    const float4 b0 = *(const float4*)&i2v_s[n * 2048 + t * 8];
    const float4 b1 = *(const float4*)&i2v_s[n * 2048 + t * 8 + 4];
    iv8[0] = b0.x; iv8[1] = b0.y; iv8[2] = b0.z; iv8[3] = b0.w;
    iv8[4] = b1.x; iv8[5] = b1.y; iv8[6] = b1.z; iv8[7] = b1.w;
    ct = cterm[n * NO + o];
  }
  float aS1[8] = {0.f, 0.f, 0.f, 0.f, 0.f, 0.f, 0.f, 0.f};
  float aS2[8] = {0.f, 0.f, 0.f, 0.f, 0.f, 0.f, 0.f, 0.f};
  float dn = 0.f, aU = 0.f;

  const float* Vb = V + (size_t)n * LL * 2048 + t * 8;

  float VA[4][8], VB[4][8], faA[4], faB[4], buA[4], buB[4];

  auto LOAD = [&](float (&Vv)[4][8], float (&fa4)[4], float (&bu4)[4],
                  const int g) {
    const int lb = c * 16 + g * 4;
#pragma unroll
    for (int u = 0; u < 4; ++u) {
      const int l = lb + u;
      const float4 v0 = *(const float4*)&Vb[(size_t)l * 2048];
      const float4 v1 = *(const float4*)&Vb[(size_t)l * 2048 + 4];
      Vv[u][0] = v0.x; Vv[u][1] = v0.y; Vv[u][2] = v0.z; Vv[u][3] = v0.w;
      Vv[u][4] = v1.x; Vv[u][5] = v1.y; Vv[u][6] = v1.z; Vv[u][7] = v1.w;
      fa4[u] = f_a[l * NB + n];
      bu4[u] = beta_use[l];
    }
  };

  auto COMP = [&](float (&Vv)[4][8], float (&fa4)[4], float (&bu4)[4],
                  const int g) {
    if (MODE != 0) {
      float tt4[4];
#pragma unroll
      for (int u = 0; u < 4; ++u) {
        float s2 = 0.f;
#pragma unroll
        for (int k = 0; k < 8; ++k) {
          const float d = Vv[u][k] - mu8[k];
          s2 = fmaf(d * d, iv8[k], s2);
        }
        s2 += __shfl_xor(s2, 1);
        s2 += __shfl_xor(s2, 2);
        s2 += __shfl_xor(s2, 4);
        tt4[u] = ct - s2;
      }
      const int sb = (g & 1) * 4;
      if (q == 0) {
#pragma unroll
        for (int u = 0; u < 4; ++u) ttl[sb + u][o] = tt4[u];
      }
      __syncthreads();
#pragma unroll
      for (int u = 0; u < 4; ++u) {
        const float vv = ttl[sb + u][t & 31];
        float m = vv;
#pragma unroll
        for (int msk = 1; msk <= 16; msk <<= 1) m = fmaxf(m, __shfl_xor(m, msk));
        float z = __expf(vv - m);
#pragma unroll
        for (int msk = 1; msk <= 16; msk <<= 1) z += __shfl_xor(z, msk);
        const float wgt = fa4[u] * __expf(tt4[u] - m) / z;
        dn += wgt;
        aU = fmaf(bu4[u], wgt, aU);
#pragma unroll
        for (int k = 0; k < 8; ++k) {
          aS1[k] = fmaf(wgt, Vv[u][k], aS1[k]);
          if (MODE != 2) {
            const float d = Vv[u][k] - mu8[k];
            aS2[k] = fmaf(wgt, d * d, aS2[k]);   // shifted around mu_prev
          }
        }
      }
    } else {
#pragma unroll
      for (int u = 0; u < 4; ++u) {
        const float wgt = fa4[u] * (1.0f / NO);
        dn += wgt;
        aU = fmaf(bu4[u], wgt, aU);
#pragma unroll
        for (int k = 0; k < 8; ++k) {
          aS1[k] = fmaf(wgt, Vv[u][k], aS1[k]);
          aS2[k] = fmaf(wgt * Vv[u][k], Vv[u][k], aS2[k]);
        }
      }
    }
  };

  // 2-deep static software pipeline over g = 0..3
  LOAD(VA, faA, buA, 0);
  LOAD(VB, faB, buB, 1);
  COMP(VA, faA, buA, 0);
  LOAD(VA, faA, buA, 2);
  COMP(VB, faB, buB, 1);
  LOAD(VB, faB, buB, 3);
  COMP(VA, faA, buA, 2);
  COMP(VB, faB, buB, 3);

  const int base = ((c * NB + n) * NO + o) * OD + q * 8;
  *(float4*)&S1p[base]     = make_float4(aS1[0], aS1[1], aS1[2], aS1[3]);
  *(float4*)&S1p[base + 4] = make_float4(aS1[4], aS1[5], aS1[6], aS1[7]);
  if (MODE != 2) {
    *(float4*)&S2p[base]     = make_float4(aS2[0], aS2[1], aS2[2], aS2[3]);
    *(float4*)&S2p[base + 4] = make_float4(aS2[4], aS2[5], aS2[6], aS2[7]);
  }
  if (q == 0) {
    dnp[(c * NB + n) * NO + o] = dn;
    aUp[(c * NB + n) * NO + o] = aU;
  }

  // ---- opportunistic last-block finalize (k4 v1 body, deterministic) ----
  __syncthreads();                       // drains all partial stores (vmcnt0)
  if (t == 0) {
    __threadfence();                     // release: device-visible partials
    const int old = atomicAdd(&cnt[n], 1);
    lastFlag = (old == MODE * 8 + 7) ? 1 : 0;
  }
  __syncthreads();
  if (lastFlag) {
    __threadfence();                     // acquire: invalidate stale cache

    if (t < 128) rA[t] = f_a[t * NB + n];
    __syncthreads();
    for (int s = 64; s >= 1; s >>= 1) {
      if (t < s) rA[t] += rA[t + s];
      __syncthreads();
    }
    const float Fsum = rA[0];

    float dnF = 0.f, aUF = 0.f;
#pragma unroll
    for (int cc = 0; cc < 8; ++cc) {
      dnF += dnp[(cc * NB + n) * NO + o];
      aUF += aUp[(cc * NB + n) * NO + o];
    }
    const float S0 = dnF;
    const float inv_den = 1.0f / (dnF + EPSF);

    float S1v[8], S2v[8];
#pragma unroll
    for (int k = 0; k < 8; ++k) { S1v[k] = 0.f; S2v[k] = 0.f; }
    for (int cc = 0; cc < 8; ++cc) {
      const int b2 = ((cc * NB + n) * NO + o) * OD + q * 8;
      const float4 u0 = *(const float4*)&S1p[b2];
      const float4 u1 = *(const float4*)&S1p[b2 + 4];
      S1v[0] += u0.x; S1v[1] += u0.y; S1v[2] += u0.z; S1v[3] += u0.w;
      S1v[4] += u1.x; S1v[5] += u1.y; S1v[6] += u1.z; S1v[7] += u1.w;
      if (MODE != 2) {
        const float4 w0 = *(const float4*)&S2p[b2];
        const float4 w1 = *(const float4*)&S2p[b2 + 4];
        S2v[0] += w0.x; S2v[1] += w0.y; S2v[2] += w0.z; S2v[3] += w0.w;
        S2v[4] += w1.x; S2v[5] += w1.y; S2v[6] += w1.z; S2v[7] += w1.w;
      }
    }
    const float aout = aUF - beta_ign[o] * (Fsum - dnF);

    if (MODE == 2) {
      if (q == 0) out[n * NO + o] = aout;
      float muv[8];
#pragma unroll
      for (int k = 0; k < 8; ++k) muv[k] = S1v[k] * inv_den;
      *(float4*)&out[2048 + n * 2048 + t * 8]     = make_float4(muv[0], muv[1], muv[2], muv[3]);
      *(float4*)&out[2048 + n * 2048 + t * 8 + 4] = make_float4(muv[4], muv[5], muv[6], muv[7]);
    } else {
      float muv[8], i2vv[8];
      float lacc = 0.f;
#pragma unroll
      for (int k = 0; k < 8; ++k) {
        muv[k] = S1v[k] * inv_den;
        const float mupk = (MODE == 0) ? 0.f : mu8[k];
        const float dd = muv[k] - mupk;
        const float varn = S2v[k] - 2.0f * dd * (S1v[k] - mupk * S0) + dd * dd * S0;
        const float var = fmaxf(varn * inv_den, 0.0f);
        i2vv[k] = 1.0f / (2.0f * var + EPSF);
        lacc += logf(var + EPSF);
      }
      *(float4*)&mu_s[n * 2048 + t * 8]      = make_float4(muv[0], muv[1], muv[2], muv[3]);
      *(float4*)&mu_s[n * 2048 + t * 8 + 4]  = make_float4(muv[4], muv[5], muv[6], muv[7]);
      *(float4*)&i2v_s[n * 2048 + t * 8]     = make_float4(i2vv[0], i2vv[1], i2vv[2], i2vv[3]);
      *(float4*)&i2v_s[n * 2048 + t * 8 + 4] = make_float4(i2vv[4], i2vv[5], i2vv[6], i2vv[7]);
      lacc += __shfl_xor(lacc, 1);
      lacc += __shfl_xor(lacc, 2);
      lacc += __shfl_xor(lacc, 4);
      if (q == 0) {
        const float lsg = fminf(aout, 0.0f) - log1pf(__expf(-fabsf(aout)));
        cterm[n * NO + o] = lsg - 0.5f * lacc;
      }
    }
  }
}

extern "C" void kernel_launch(void* const* d_in, const int* in_sizes, int n_in,
                              void* d_out, int out_size, void* d_ws, size_t ws_size,
                              hipStream_t stream) {
  const float* x        = (const float*)d_in[0];
  const float* Wscore   = (const float*)d_in[1];
  const float* Bscore   = (const float*)d_in[2];
  const float* Wcap     = (const float*)d_in[3];
  const float* Bcap     = (const float*)d_in[4];
  const float* Wvote    = (const float*)d_in[5];
  const float* Bvote    = (const float*)d_in[6];
  const float* beta_use = (const float*)d_in[7];
  const float* beta_ign = (const float*)d_in[8];
  // d_in[9] = iters (fixed at 3 by setup; graph capture forbids readback)
  float* out = (float*)d_out;

  float* ws     = (float*)d_ws;
  float* V      = ws;                        // 16777216 fp32
  float* Cpart  = ws;                        // aliases V (pre-k1)
  float* apart  = ws + 3145728;              // aliases V (pre-k1)
  ushort_t* Ah  = (ushort_t*)(ws + 16777216);    // 524288 ushorts
  ushort_t* Al  = Ah + 524288;                   // 524288 ushorts
  float* f_a    = ws + 16777216 + 524288;    // 8192
  float* S1p    = f_a + 8192;                // 1048576
  float* S2p    = S1p + 1048576;             // 1048576
  float* dnp    = S2p + 1048576;             // 16384
  float* aUp    = dnp + 16384;               // 16384
  float* mu_s   = aUp + 16384;               // 131072
  float* i2v_s  = mu_s + 131072;             // 131072
  float* ct     = i2v_s + 131072;            // 2048
  int*   cnt    = (int*)(ct + 2048);         // 64 ints
  const size_t need = (size_t)(16777216 + 524288 + 8192 + 2 * 1048576 +
                               2 * 16384 + 2 * 131072 + 2048 + 64) * sizeof(float);
  if (ws_size < need) return;

  k0a_proj<<<768, 256, 0, stream>>>(x, Wscore, Wcap, Cpart, apart);
  k0bc<<<512, 256, 0, stream>>>(Cpart, Bcap, apart, Bscore, Ah, Al, f_a, cnt);
  k1_votes<<<2048, 256, 0, stream>>>(Ah, Al, Wvote, Bvote, V);
  k3f_em<0><<<512, 256, 0, stream>>>(V, f_a, beta_use, beta_ign, mu_s, i2v_s,
                                     ct, S1p, S2p, dnp, aUp, out, cnt);
  k3f_em<1><<<512, 256, 0, stream>>>(V, f_a, beta_use, beta_ign, mu_s, i2v_s,
                                     ct, S1p, S2p, dnp, aUp, out, cnt);
  k3f_em<2><<<512, 256, 0, stream>>>(V, f_a, beta_use, beta_ign, mu_s, i2v_s,
                                     ct, S1p, S2p, dnp, aUp, out, cnt);
}

// Round 8
// 240.659 us; speedup vs baseline: 1.3698x; 1.3698x over previous
//
#include <hip/hip_runtime.h>
#include <math.h>

#define NB 64      // batch N
#define LL 128     // n_in capsules
#define DD 768     // feature dim
#define ID 64      // in_dim
#define OD 64      // out_dim
#define NO 32      // n_out
#define EPSF 1e-8f

typedef unsigned short ushort_t;
typedef __attribute__((ext_vector_type(8))) short bf16x8;
typedef __attribute__((ext_vector_type(4))) float f32x4;

// ws layout (floats):
//  V     : 16777216 fp32  [n][l][o*64+j]
//    Cpart/apart alias V front (consumed pre-k1)
//  Ah/Al : 2 x 524288 ushorts, fragment-linear [l][ks][mt][mr][q][i8]
//  f_a   : 8192
//  S1p/S2p : 8-chunk partials [c][n][o][j] (1048576 each)
//  dnp/aUp : 16384 each
//  mu_s/i2v_s : 131072 each ; cterm : 2048

__device__ __forceinline__ float gelu_exact(float v) {
  return 0.5f * v * (1.0f + erff(v * 0.70710678118654752440f));
}
__device__ __forceinline__ float sigmoidf_(float z) {
  return 1.0f / (1.0f + __expf(-z));
}
__device__ __forceinline__ unsigned short f2bf(float f) {  // RNE
  unsigned u = __float_as_uint(f);
  unsigned r = (u + 0x7FFFu + ((u >> 16) & 1u)) >> 16;
  return (unsigned short)r;
}
__device__ __forceinline__ float bf2f(unsigned short s) {
  return __uint_as_float(((unsigned)s) << 16);
}

// ---------------- k0a: split-K partial GEMM for the projections (unchanged).
__global__ __launch_bounds__(256) void k0a_proj(
    const float* __restrict__ x, const float* __restrict__ Wscore,
    const float* __restrict__ Wcap,
    float* __restrict__ Cpart, float* __restrict__ apart)
{
  const int l  = blockIdx.x & 127;
  const int kc = blockIdx.x >> 7;
  const int t = threadIdx.x;
  const int tn = t >> 4;
  const int ti = t & 15;
  __shared__ float Xs[64][68];
  __shared__ float Ws[64][68];
  __shared__ float Ss[64];
  float C[4][4] = {{0.f}};
  float asum[4] = {0.f, 0.f, 0.f, 0.f};

  for (int kt = 0; kt < 2; ++kt) {
    const int kbase = kc * 128 + kt * 64;
#pragma unroll
    for (int r = 0; r < 4; ++r) {
      const int flat = r * 1024 + t * 4;
      const int p = flat >> 6, qq = flat & 63;
      *(float4*)&Xs[p][qq] = *(const float4*)&x[(p * LL + l) * DD + kbase + qq];
      *(float4*)&Ws[p][qq] = *(const float4*)&Wcap[(l * DD + kbase + p) * ID + qq];
    }
    if (t < 16)
      *(float4*)&Ss[4 * t] = *(const float4*)&Wscore[l * DD + kbase + 4 * t];
    __syncthreads();
#pragma unroll 8
    for (int k = 0; k < 64; ++k) {
      float av[4];
      av[0] = Xs[4 * tn + 0][k];
      av[1] = Xs[4 * tn + 1][k];
      av[2] = Xs[4 * tn + 2][k];
      av[3] = Xs[4 * tn + 3][k];
      const float4 b = *(const float4*)&Ws[k][4 * ti];
      const float sk = Ss[k];
#pragma unroll
      for (int a = 0; a < 4; ++a) {
        C[a][0] = fmaf(av[a], b.x, C[a][0]);
        C[a][1] = fmaf(av[a], b.y, C[a][1]);
        C[a][2] = fmaf(av[a], b.z, C[a][2]);
        C[a][3] = fmaf(av[a], b.w, C[a][3]);
        asum[a] = fmaf(av[a], sk, asum[a]);
      }
    }
    __syncthreads();
  }
#pragma unroll
  for (int a = 0; a < 4; ++a)
    *(float4*)&Cpart[kc * 524288 + (l * 64 + 4 * tn + a) * 64 + 4 * ti] =
        make_float4(C[a][0], C[a][1], C[a][2], C[a][3]);
  if (ti == 0) {
#pragma unroll
    for (int a = 0; a < 4; ++a)
      apart[kc * 8192 + l * 64 + 4 * tn + a] = asum[a];
  }
}

// ---------------- k0bc: fused (k0b reduce+gelu -> Ah/Al) + (k0c -> f_a).
// Blocks 0..31 also do the f_a element.  Verified correct in R7; kept.
__global__ __launch_bounds__(256) void k0bc(
    const float* __restrict__ Cpart, const float* __restrict__ Bcap,
    const float* __restrict__ apart, const float* __restrict__ Bscore,
    ushort_t* __restrict__ Ah, ushort_t* __restrict__ Al,
    float* __restrict__ f_a)
{
  const int bid = blockIdx.x;
  const int t = threadIdx.x;
  const int e = (bid * 256 + t) * 4;
  float4 s = *(const float4*)&Cpart[e];
#pragma unroll
  for (int kc = 1; kc < 6; ++kc) {
    const float4 p = *(const float4*)&Cpart[kc * 524288 + e];
    s.x += p.x; s.y += p.y; s.z += p.z; s.w += p.w;
  }
  const int l = e >> 12;
  const int n = (e >> 6) & 63;
  const int i0 = e & 63;
  const float4 bc = *(const float4*)&Bcap[l * 64 + i0];
  float m[4] = {gelu_exact(s.x + bc.x), gelu_exact(s.y + bc.y),
                gelu_exact(s.z + bc.z), gelu_exact(s.w + bc.w)};
  ushort4 h, lo;
  h.x = f2bf(m[0]); lo.x = f2bf(m[0] - bf2f(h.x));
  h.y = f2bf(m[1]); lo.y = f2bf(m[1] - bf2f(h.y));
  h.z = f2bf(m[2]); lo.z = f2bf(m[2] - bf2f(h.z));
  h.w = f2bf(m[3]); lo.w = f2bf(m[3] - bf2f(h.w));
  const int off = l * 4096 + (i0 >> 5) * 2048 + (n >> 4) * 512 + (n & 15) * 32 +
                  ((i0 >> 3) & 3) * 8 + (i0 & 7);
  *(ushort4*)&Ah[off] = h;
  *(ushort4*)&Al[off] = lo;

  if (bid < 32) {                     // k0c work
    const int e2 = bid * 256 + t;
    float ss = 0.f;
#pragma unroll
    for (int kc = 0; kc < 6; ++kc) ss += apart[kc * 8192 + e2];
    f_a[e2] = sigmoidf_(ss + Bscore[e2 >> 6]);
  }
}

// ---------------- k1: V = mu_in @ Wvote + Bvote (unchanged from R6 v6).
__global__ __launch_bounds__(256) void k1_votes(
    const ushort_t* __restrict__ Ah, const ushort_t* __restrict__ Al,
    const float* __restrict__ Wvote, const float* __restrict__ Bvote,
    float* __restrict__ V)
{
  const int t = threadIdx.x;
  const int w = t >> 6;
  const int lane = t & 63;
  const int g = blockIdx.x * 4 + w;       // 0..8191
  const int pair = g >> 1;                // l*NO + o
  const int jh = g & 1;                   // j-half
  const int l = pair >> 5;
  const int mr = lane & 15, q = lane >> 4;

  __shared__ unsigned HL_all[4][1024];    // per-wave staging, 4 KiB/wave
  unsigned* HL = HL_all[w];

  const float* Wt = Wvote + (size_t)pair * 4096 + jh * 32;   // [i][j-half]
  const int afoff = mr * 32 + q * 8;

  float bv[2];
#pragma unroll
  for (int nt = 0; nt < 2; ++nt)
    bv[nt] = Bvote[pair * 64 + jh * 32 + 16 * nt + mr];

  f32x4 acc[4][2];
#pragma unroll
  for (int mt = 0; mt < 4; ++mt)
#pragma unroll
    for (int nt = 0; nt < 2; ++nt) {
      f32x4 z = {0.f, 0.f, 0.f, 0.f};
      acc[mt][nt] = z;
    }

#pragma unroll 1
  for (int ks = 0; ks < 2; ++ks) {
#pragma unroll
    for (int f = 0; f < 4; ++f) {
      const int idx = f * 64 + lane;
      const int r = idx >> 3;                       // row 0..31
      const int c4 = (idx & 7) * 4;                 // col 0..28
      const float4 v4 = *(const float4*)&Wt[ks * 2048 + r * 64 + c4];
      const int jc = c4 ^ ((r & 8) << 1);           // XOR-swizzled col base
      const float e4[4] = {v4.x, v4.y, v4.z, v4.w};
      unsigned pk[4];
#pragma unroll
      for (int d = 0; d < 4; ++d) {
        const unsigned short hi = f2bf(e4[d]);
        const unsigned short lo = f2bf(e4[d] - bf2f(hi));
        pk[d] = (unsigned)hi | ((unsigned)lo << 16);
      }
      *(uint4*)&HL[r * 32 + jc] = make_uint4(pk[0], pk[1], pk[2], pk[3]);
    }

    bf16x8 afh[4], afl[4];
#pragma unroll
    for (int mt = 0; mt < 4; ++mt) {
      const int off = l * 4096 + ks * 2048 + mt * 512 + afoff;
      afh[mt] = *(const bf16x8*)&Ah[off];
      afl[mt] = *(const bf16x8*)&Al[off];
    }

#pragma unroll
    for (int nt = 0; nt < 2; ++nt) {
      const int j = 16 * nt + mr;
      unsigned wv[8];
#pragma unroll
      for (int d = 0; d < 8; ++d) {
        const int ii = q * 8 + d;
        wv[d] = HL[ii * 32 + (j ^ ((ii & 8) << 1))];
      }
      union { ushort_t u[8]; bf16x8 v; } bh, bl;
#pragma unroll
      for (int d = 0; d < 8; ++d) {
        bh.u[d] = (ushort_t)(wv[d] & 0xffffu);
        bl.u[d] = (ushort_t)(wv[d] >> 16);
      }
#pragma unroll
      for (int mt = 0; mt < 4; ++mt) {
        acc[mt][nt] = __builtin_amdgcn_mfma_f32_16x16x32_bf16(
            afh[mt], bh.v, acc[mt][nt], 0, 0, 0);
        acc[mt][nt] = __builtin_amdgcn_mfma_f32_16x16x32_bf16(
            afh[mt], bl.v, acc[mt][nt], 0, 0, 0);
        acc[mt][nt] = __builtin_amdgcn_mfma_f32_16x16x32_bf16(
            afl[mt], bh.v, acc[mt][nt], 0, 0, 0);
      }
    }
  }

  float* T = (float*)HL;
#pragma unroll
  for (int mt = 0; mt < 4; ++mt) {
#pragma unroll
    for (int nt = 0; nt < 2; ++nt)
#pragma unroll
      for (int r = 0; r < 4; ++r)
        T[(4 * q + r) * 36 + 16 * nt + mr] = acc[mt][nt][r] + bv[nt];
#pragma unroll
    for (int rr = 0; rr < 2; ++rr) {
      const int row = rr * 8 + (lane >> 3);
      const int c4e = (lane & 7) * 4;
      const float4 vv = *(const float4*)&T[row * 36 + c4e];
      const size_t base = (size_t)(16 * mt + row) * (LL * NO * OD) +
                          (size_t)pair * 64 + jh * 32 + c4e;
      *(float4*)&V[base] = vv;
    }
  }
}

// ---------------- k3: fused log_p -> softmax(R over o) -> em accumulate.
// R6 v5 pipelined source restored (R7's finisher fusion demoted the VA/VB
// pipeline buffers to scratch: VGPR 56, VALUBusy 1.5%, 2.2x slower).
// Only change vs R6: mode==2 (final iter) skips the S2p stores -- the
// reference discards the final var_out.  aS2 still computed (hot loop
// codegen untouched); uniform runtime branch around 2 stores only.
__global__ __launch_bounds__(256) void k3_em(
    const float* __restrict__ V, const float* __restrict__ f_a,
    const float* __restrict__ beta_use, const float* __restrict__ mu_s,
    const float* __restrict__ i2v_s, const float* __restrict__ cterm,
    float* __restrict__ S1p, float* __restrict__ S2p,
    float* __restrict__ dnp, float* __restrict__ aUp, const int mode)
{
  const int n = blockIdx.x >> 3;
  const int c = blockIdx.x & 7;
  const int t = threadIdx.x;
  const int o = t >> 3, q = t & 7;
  __shared__ float ttl[8][32];

  float mu8[8], iv8[8];
  float ct = 0.f;
  if (mode) {
    const float4 a0 = *(const float4*)&mu_s[n * 2048 + t * 8];
    const float4 a1 = *(const float4*)&mu_s[n * 2048 + t * 8 + 4];
    mu8[0] = a0.x; mu8[1] = a0.y; mu8[2] = a0.z; mu8[3] = a0.w;
    mu8[4] = a1.x; mu8[5] = a1.y; mu8[6] = a1.z; mu8[7] = a1.w;
    const float4 b0 = *(const float4*)&i2v_s[n * 2048 + t * 8];
    const float4 b1 = *(const float4*)&i2v_s[n * 2048 + t * 8 + 4];
    iv8[0] = b0.x; iv8[1] = b0.y; iv8[2] = b0.z; iv8[3] = b0.w;
    iv8[4] = b1.x; iv8[5] = b1.y; iv8[6] = b1.z; iv8[7] = b1.w;
    ct = cterm[n * NO + o];
  }
  float aS1[8] = {0.f, 0.f, 0.f, 0.f, 0.f, 0.f, 0.f, 0.f};
  float aS2[8] = {0.f, 0.f, 0.f, 0.f, 0.f, 0.f, 0.f, 0.f};
  float dn = 0.f, aU = 0.f;

  const float* Vb = V + (size_t)n * LL * 2048 + t * 8;

  float VA[4][8], VB[4][8], faA[4], faB[4], buA[4], buB[4];

  auto LOAD = [&](float (&Vv)[4][8], float (&fa4)[4], float (&bu4)[4],
                  const int g) {
    const int lb = c * 16 + g * 4;
#pragma unroll
    for (int u = 0; u < 4; ++u) {
      const int l = lb + u;
      const float4 v0 = *(const float4*)&Vb[(size_t)l * 2048];
      const float4 v1 = *(const float4*)&Vb[(size_t)l * 2048 + 4];
      Vv[u][0] = v0.x; Vv[u][1] = v0.y; Vv[u][2] = v0.z; Vv[u][3] = v0.w;
      Vv[u][4] = v1.x; Vv[u][5] = v1.y; Vv[u][6] = v1.z; Vv[u][7] = v1.w;
      fa4[u] = f_a[l * NB + n];
      bu4[u] = beta_use[l];
    }
  };

  auto COMP = [&](float (&Vv)[4][8], float (&fa4)[4], float (&bu4)[4],
                  const int g) {
    if (mode) {
      float tt4[4];
#pragma unroll
      for (int u = 0; u < 4; ++u) {
        float s2 = 0.f;
#pragma unroll
        for (int k = 0; k < 8; ++k) {
          const float d = Vv[u][k] - mu8[k];
          s2 = fmaf(d * d, iv8[k], s2);
        }
        s2 += __shfl_xor(s2, 1);
        s2 += __shfl_xor(s2, 2);
        s2 += __shfl_xor(s2, 4);
        tt4[u] = ct - s2;
      }
      const int sb = (g & 1) * 4;
      if (q == 0) {
#pragma unroll
        for (int u = 0; u < 4; ++u) ttl[sb + u][o] = tt4[u];
      }
      __syncthreads();
#pragma unroll
      for (int u = 0; u < 4; ++u) {
        const float vv = ttl[sb + u][t & 31];
        float m = vv;
#pragma unroll
        for (int msk = 1; msk <= 16; msk <<= 1) m = fmaxf(m, __shfl_xor(m, msk));
        float z = __expf(vv - m);
#pragma unroll
        for (int msk = 1; msk <= 16; msk <<= 1) z += __shfl_xor(z, msk);
        const float wgt = fa4[u] * __expf(tt4[u] - m) / z;
        dn += wgt;
        aU = fmaf(bu4[u], wgt, aU);
#pragma unroll
        for (int k = 0; k < 8; ++k) {
          const float d = Vv[u][k] - mu8[k];
          aS1[k] = fmaf(wgt, Vv[u][k], aS1[k]);
          aS2[k] = fmaf(wgt, d * d, aS2[k]);   // shifted around mu_prev
        }
      }
    } else {
#pragma unroll
      for (int u = 0; u < 4; ++u) {
        const float wgt = fa4[u] * (1.0f / NO);
        dn += wgt;
        aU = fmaf(bu4[u], wgt, aU);
#pragma unroll
        for (int k = 0; k < 8; ++k) {
          aS1[k] = fmaf(wgt, Vv[u][k], aS1[k]);
          aS2[k] = fmaf(wgt * Vv[u][k], Vv[u][k], aS2[k]);
        }
      }
    }
  };

  // 2-deep static software pipeline over g = 0..3
  LOAD(VA, faA, buA, 0);
  LOAD(VB, faB, buB, 1);
  COMP(VA, faA, buA, 0);
  LOAD(VA, faA, buA, 2);
  COMP(VB, faB, buB, 1);
  LOAD(VB, faB, buB, 3);
  COMP(VA, faA, buA, 2);
  COMP(VB, faB, buB, 3);

  const int base = ((c * NB + n) * NO + o) * OD + q * 8;
  *(float4*)&S1p[base]     = make_float4(aS1[0], aS1[1], aS1[2], aS1[3]);
  *(float4*)&S1p[base + 4] = make_float4(aS1[4], aS1[5], aS1[6], aS1[7]);
  if (mode != 2) {
    *(float4*)&S2p[base]     = make_float4(aS2[0], aS2[1], aS2[2], aS2[3]);
    *(float4*)&S2p[base + 4] = make_float4(aS2[4], aS2[5], aS2[6], aS2[7]);
  }
  if (q == 0) {
    dnp[(c * NB + n) * NO + o] = dn;
    aUp[(c * NB + n) * NO + o] = aU;
  }
}

// ---------------- k4: finalize.  R6 v2 (one wave per (n,o), grid 2048).
// Change vs R6: final_iter skips the S2p loads, mup load, and the whole
// var/i2v/log chain (dead in final iteration -- outputs are aout/mu only).
__global__ __launch_bounds__(64) void k4_fin23(
    const float* __restrict__ S1p, const float* __restrict__ S2p,
    const float* __restrict__ dnp, const float* __restrict__ aUp,
    const float* __restrict__ f_a, const float* __restrict__ beta_ign,
    float* __restrict__ mu_s, float* __restrict__ i2v_s, float* __restrict__ cterm,
    float* __restrict__ out, const int final_iter, const int first)
{
  const int n = blockIdx.x >> 5;     // 0..63
  const int o = blockIdx.x & 31;     // 0..31
  const int j = threadIdx.x;         // 0..63

  // Fsum over l (128): first level pairs l and l+64, then xor-tree desc.
  float fs = f_a[j * NB + n] + f_a[(j + 64) * NB + n];
#pragma unroll
  for (int msk = 32; msk >= 1; msk >>= 1) fs += __shfl_xor(fs, msk);
  const float Fsum = fs;

  float dn = 0.f, aU = 0.f;
#pragma unroll
  for (int cc = 0; cc < 8; ++cc) {
    dn += dnp[(cc * NB + n) * NO + o];
    aU += aUp[(cc * NB + n) * NO + o];
  }
  const float S0 = dn;
  const float inv_den = 1.0f / (dn + EPSF);

  float S1 = 0.f;
#pragma unroll
  for (int cc = 0; cc < 8; ++cc)
    S1 += S1p[((cc * NB + n) * NO + o) * OD + j];

  const float aout = aU - beta_ign[o] * (Fsum - dn);
  const float mu = S1 * inv_den;

  if (final_iter) {
    if (j == 0) out[n * NO + o] = aout;
    out[2048 + n * 2048 + o * 64 + j] = mu;
  } else {
    float S2 = 0.f;
#pragma unroll
    for (int cc = 0; cc < 8; ++cc)
      S2 += S2p[((cc * NB + n) * NO + o) * OD + j];
    const float mup = first ? 0.f : mu_s[n * 2048 + o * 64 + j];
    const float dd = mu - mup;
    const float varn = S2 - 2.0f * dd * (S1 - mup * S0) + dd * dd * S0;
    const float var = fmaxf(varn * inv_den, 0.0f);
    mu_s[n * 2048 + o * 64 + j] = mu;
    i2v_s[n * 2048 + o * 64 + j] = 1.0f / (2.0f * var + EPSF);
    float lacc = logf(var + EPSF);
#pragma unroll
    for (int msk = 32; msk >= 1; msk >>= 1) lacc += __shfl_xor(lacc, msk);
    if (j == 0) {
      const float lsg = fminf(aout, 0.0f) - log1pf(__expf(-fabsf(aout)));
      cterm[n * NO + o] = lsg - 0.5f * lacc;
    }
  }
}

extern "C" void kernel_launch(void* const* d_in, const int* in_sizes, int n_in,
                              void* d_out, int out_size, void* d_ws, size_t ws_size,
                              hipStream_t stream) {
  const float* x        = (const float*)d_in[0];
  const float* Wscore   = (const float*)d_in[1];
  const float* Bscore   = (const float*)d_in[2];
  const float* Wcap     = (const float*)d_in[3];
  const float* Bcap     = (const float*)d_in[4];
  const float* Wvote    = (const float*)d_in[5];
  const float* Bvote    = (const float*)d_in[6];
  const float* beta_use = (const float*)d_in[7];
  const float* beta_ign = (const float*)d_in[8];
  // d_in[9] = iters (fixed at 3 by setup; graph capture forbids readback)
  float* out = (float*)d_out;

  float* ws     = (float*)d_ws;
  float* V      = ws;                        // 16777216 fp32
  float* Cpart  = ws;                        // aliases V (pre-k1)
  float* apart  = ws + 3145728;              // aliases V (pre-k1)
  ushort_t* Ah  = (ushort_t*)(ws + 16777216);    // 524288 ushorts
  ushort_t* Al  = Ah + 524288;                   // 524288 ushorts
  float* f_a    = ws + 16777216 + 524288;    // 8192
  float* S1p    = f_a + 8192;                // 1048576
  float* S2p    = S1p + 1048576;             // 1048576
  float* dnp    = S2p + 1048576;             // 16384
  float* aUp    = dnp + 16384;               // 16384
  float* mu_s   = aUp + 16384;               // 131072
  float* i2v_s  = mu_s + 131072;             // 131072
  float* ct     = i2v_s + 131072;            // 2048
  const size_t need = (size_t)(16777216 + 524288 + 8192 + 2 * 1048576 +
                               2 * 16384 + 2 * 131072 + 2048) * sizeof(float);
  if (ws_size < need) return;

  k0a_proj<<<768, 256, 0, stream>>>(x, Wscore, Wcap, Cpart, apart);
  k0bc<<<512, 256, 0, stream>>>(Cpart, Bcap, apart, Bscore, Ah, Al, f_a);
  k1_votes<<<2048, 256, 0, stream>>>(Ah, Al, Wvote, Bvote, V);
  // iter 1 (uniform R)
  k3_em<<<512, 256, 0, stream>>>(V, f_a, beta_use, mu_s, i2v_s, ct, S1p, S2p, dnp, aUp, 0);
  k4_fin23<<<2048, 64, 0, stream>>>(S1p, S2p, dnp, aUp, f_a, beta_ign, mu_s, i2v_s, ct, out, 0, 1);
  // iter 2
  k3_em<<<512, 256, 0, stream>>>(V, f_a, beta_use, mu_s, i2v_s, ct, S1p, S2p, dnp, aUp, 1);
  k4_fin23<<<2048, 64, 0, stream>>>(S1p, S2p, dnp, aUp, f_a, beta_ign, mu_s, i2v_s, ct, out, 0, 0);
  // iter 3 (final; mode 2 = no S2 stores, k4 skips var path)
  k3_em<<<512, 256, 0, stream>>>(V, f_a, beta_use, mu_s, i2v_s, ct, S1p, S2p, dnp, aUp, 2);
  k4_fin23<<<2048, 64, 0, stream>>>(S1p, S2p, dnp, aUp, f_a, beta_ign, mu_s, i2v_s, ct, out, 1, 0);
}